// Round 2
// baseline (515.163 us; speedup 1.0000x reference)
//
#include <hip/hip_runtime.h>

// Sorted-segment product:
//   out[i] = prod_{j : csr[j]==i} x[ptrs[j]]   (empty segment -> 0)
//
// csr is sorted -> each segment is a contiguous run; thread owns runs that
// START in its K-edge chunk; no atomics, every out element written once.
//
// R2 change: csr/ptrs chunk loads and out stores are NON-TEMPORAL so the
// 128 MB of streaming index data doesn't evict x lines from per-XCD L2.
// The x-gather (random, reused ~32x/line) keeps normal caching priority.

#define K 8  // edges per thread; E=16.7M -> 2.1M threads

typedef int v4i __attribute__((ext_vector_type(4)));

__global__ __launch_bounds__(256) void prodseg_kernel(
    const float* __restrict__ x,
    const int*   __restrict__ ptrs,
    const int*   __restrict__ csr,
    float*       __restrict__ out,
    int E, int S)
{
    int t = blockIdx.x * blockDim.x + threadIdx.x;
    int base = t * K;
    if (base >= E) return;

    // segment id just before our chunk (-1 sentinel at array start).
    // Neighbor-thread's line -> L1/L2 hit; keep as a normal load.
    int prev = (base == 0) ? -1 : csr[base - 1];

    int   seg[K];
    int   pt[K];
    float g[K];
    int n;

    if (base + K <= E) {
        n = K;
        // base is a multiple of 8 -> 32B aligned, vec4 loads are safe
        const v4i* c4 = reinterpret_cast<const v4i*>(csr + base);
        v4i c0 = __builtin_nontemporal_load(c4);
        v4i c1 = __builtin_nontemporal_load(c4 + 1);
        seg[0]=c0.x; seg[1]=c0.y; seg[2]=c0.z; seg[3]=c0.w;
        seg[4]=c1.x; seg[5]=c1.y; seg[6]=c1.z; seg[7]=c1.w;
        const v4i* p4 = reinterpret_cast<const v4i*>(ptrs + base);
        v4i p0 = __builtin_nontemporal_load(p4);
        v4i p1 = __builtin_nontemporal_load(p4 + 1);
        pt[0]=p0.x; pt[1]=p0.y; pt[2]=p0.z; pt[3]=p0.w;
        pt[4]=p1.x; pt[5]=p1.y; pt[6]=p1.z; pt[7]=p1.w;
    } else {
        n = E - base;
        for (int k = 0; k < K; ++k) {
            int idx = base + (k < n ? k : 0);
            seg[k] = csr[idx];
            pt[k]  = ptrs[idx];
        }
    }

    // issue all gathers up front so their latencies overlap.
    // NORMAL loads: x lines have reuse, we want them resident in L2.
    #pragma unroll
    for (int k = 0; k < K; ++k) g[k] = x[pt[k]];

    int   cur = seg[0];
    bool  own = (cur != prev);
    float prod = own ? g[0] : 1.0f;
    if (own) {
        // zero the empty-segment gap before our first owned run
        for (int q = prev + 1; q < cur; ++q)
            __builtin_nontemporal_store(0.0f, out + q);
    }

    #pragma unroll
    for (int k = 1; k < K; ++k) {
        if (k >= n) break;
        int s = seg[k];
        if (s == cur) {
            prod *= g[k];             // harmless if !own (never stored)
        } else {
            if (own) __builtin_nontemporal_store(prod, out + cur);
            // zero empty segments between cur and s (new run start is ours)
            for (int q = cur + 1; q < s; ++q)
                __builtin_nontemporal_store(0.0f, out + q);
            cur  = s;
            own  = true;
            prod = g[k];
        }
    }

    // final run of the chunk: if owned, walk forward across chunk boundary
    if (own) {
        int idx = base + n;
        while (idx < E && csr[idx] == cur) {
            prod *= x[ptrs[idx]];
            ++idx;
        }
        __builtin_nontemporal_store(prod, out + cur);
        // if we owned the very last segment, zero any trailing out elements
        if (idx == E) {
            for (int q = cur + 1; q < S; ++q)
                __builtin_nontemporal_store(0.0f, out + q);
        }
    }
}

extern "C" void kernel_launch(void* const* d_in, const int* in_sizes, int n_in,
                              void* d_out, int out_size, void* d_ws, size_t ws_size,
                              hipStream_t stream) {
    const float* x    = (const float*)d_in[0];
    const int*   ptrs = (const int*)d_in[1];
    const int*   csr  = (const int*)d_in[2];
    float*       out  = (float*)d_out;
    int E = in_sizes[1];
    int S = out_size;

    int nthreads = (E + K - 1) / K;
    dim3 block(256);
    dim3 grid((nthreads + block.x - 1) / block.x);
    prodseg_kernel<<<grid, block, 0, stream>>>(x, ptrs, csr, out, E, S);
}

// Round 3
// 333.481 us; speedup vs baseline: 1.5448x; 1.5448x over previous
//
#include <hip/hip_runtime.h>

// Sorted-segment product: out[i] = prod_{j: csr[j]==i} x[ptrs[j]], empty -> 0.
//
// R3: window-phased gather. All waves sweep x in 1 MB windows so the active
// window is L2-resident on every XCD; gathers become L2 hits instead of
// ~64B/edge fabric fills (was 1.26 GB of 1.39 GB FETCH).
//
// Persistent grid: 512 blocks x 512 threads (2 blocks/CU, LDS 64 KB each).
// Thread holds its 32 ptrs + 32 gathered values in registers; values are
// mirrored to LDS (column-major, bank-conflict-free) so neighbor threads can
// walk runs that cross chunk boundaries. Ownership logic identical to the
// R1 kernel (absmax 0.0): a thread owns runs starting in its chunk; the
// owner also zero-fills preceding empty segments; every out element is
// written exactly once.

#define EPT    32                 // edges per thread
#define BLK    512                // threads per block
#define MSC    (BLK * EPT)        // 16384 edges per superchunk
#define NBLK   512                // persistent blocks (2 per CU)
#define WSHIFT 18                 // window = 2^18 floats = 1 MB

__global__ __launch_bounds__(BLK, 4) void prodseg_main(
    const float* __restrict__ x,
    const int*   __restrict__ ptrs,
    const int*   __restrict__ csr,
    float*       __restrict__ out,
    int E, int S, int F /* # full superchunks */, int nwin)
{
    __shared__ float gbuf[MSC];   // column-major: edge (t,k) -> gbuf[k*BLK + t]
    const int t = threadIdx.x;
    const int ngen = (F + (int)gridDim.x - 1) / (int)gridDim.x;

    for (int gen = 0; gen < ngen; ++gen) {
        int sc = gen * (int)gridDim.x + (int)blockIdx.x;
        if (sc >= F) break;                    // block-uniform exit
        const int sbase = sc * MSC;
        const int gbase = sbase + t * EPT;

        // ---- stage my 32 ptrs into registers (vectorized, aligned) ----
        int pt[EPT];
        {
            const int4* p4 = reinterpret_cast<const int4*>(ptrs + gbase);
            #pragma unroll
            for (int i = 0; i < EPT / 4; ++i) {
                int4 v = p4[i];
                pt[4*i+0] = v.x; pt[4*i+1] = v.y;
                pt[4*i+2] = v.z; pt[4*i+3] = v.w;
            }
        }

        // ---- window-phased gather ----
        float g[EPT];
        for (int w = 0; w < nwin; ++w) {
            // 1) predicated loads only — independent, all issue (MLP)
            #pragma unroll
            for (int k = 0; k < EPT; ++k)
                if ((pt[k] >> WSHIFT) == w) g[k] = x[pt[k]];
            // 2) mirror to LDS for cross-thread walks
            #pragma unroll
            for (int k = 0; k < EPT; ++k)
                if ((pt[k] >> WSHIFT) == w) gbuf[k * BLK + t] = g[k];
            // keep the block's waves phase-aligned (L2 locality);
            // also the final one orders gbuf writes before product reads
            __syncthreads();
        }

        // ---- product phase (run ownership, exact) ----
        int prev = (gbase == 0) ? -1 : csr[gbase - 1];
        const int4* c4 = reinterpret_cast<const int4*>(csr + gbase);
        int cur = 0; bool own = false; float prod = 1.0f;
        #pragma unroll
        for (int i = 0; i < EPT / 4; ++i) {
            int4 c = c4[i];
            int sv[4] = {c.x, c.y, c.z, c.w};
            #pragma unroll
            for (int j = 0; j < 4; ++j) {
                const int k = 4 * i + j;
                int sg = sv[j];
                if (k == 0) {
                    cur = sg; own = (sg != prev);
                    prod = own ? g[0] : 1.0f;
                    if (own)
                        for (int q = prev + 1; q < cur; ++q) out[q] = 0.0f;
                } else {
                    if (sg == cur) {
                        prod *= g[k];          // harmless if !own (never stored)
                    } else {
                        if (own) out[cur] = prod;
                        for (int q = cur + 1; q < sg; ++q) out[q] = 0.0f;
                        cur = sg; own = true; prod = g[k];
                    }
                }
            }
        }
        // final run: walk forward; in-superchunk values come from LDS
        if (own) {
            int idx = gbase + EPT;
            while (idx < E) {
                if (csr[idx] != cur) break;
                float v;
                int local = idx - sbase;
                if (local < MSC)
                    v = gbuf[(local & (EPT - 1)) * BLK + (local >> 5)];
                else
                    v = x[ptrs[idx]];
                prod *= v; ++idx;
            }
            out[cur] = prod;
            if (idx == E)
                for (int q = cur + 1; q < S; ++q) out[q] = 0.0f;
        }
        __syncthreads();   // protect gbuf before next generation
    }
}

// Generic tail (E % MSC != 0) — R1-proven logic; not launched for E = 2^24.
#define TK 8
__global__ __launch_bounds__(256) void prodseg_tail(
    const float* __restrict__ x,
    const int*   __restrict__ ptrs,
    const int*   __restrict__ csr,
    float*       __restrict__ out,
    int E0, int E, int S)
{
    int t = blockIdx.x * blockDim.x + threadIdx.x;
    int base = E0 + t * TK;
    if (base >= E) return;
    int prev = (base == 0) ? -1 : csr[base - 1];
    int n = (base + TK <= E) ? TK : (E - base);

    int cur = 0; bool own = false; float prod = 1.0f;
    for (int k = 0; k < n; ++k) {
        int sg = csr[base + k];
        float gv = x[ptrs[base + k]];
        if (k == 0) {
            cur = sg; own = (sg != prev);
            prod = own ? gv : 1.0f;
            if (own) for (int q = prev + 1; q < cur; ++q) out[q] = 0.0f;
        } else if (sg == cur) {
            prod *= gv;
        } else {
            if (own) out[cur] = prod;
            for (int q = cur + 1; q < sg; ++q) out[q] = 0.0f;
            cur = sg; own = true; prod = gv;
        }
    }
    if (own) {
        int idx = base + n;
        while (idx < E && csr[idx] == cur) { prod *= x[ptrs[idx]]; ++idx; }
        out[cur] = prod;
        if (idx == E) for (int q = cur + 1; q < S; ++q) out[q] = 0.0f;
    }
}

extern "C" void kernel_launch(void* const* d_in, const int* in_sizes, int n_in,
                              void* d_out, int out_size, void* d_ws, size_t ws_size,
                              hipStream_t stream) {
    const float* x    = (const float*)d_in[0];
    const int*   ptrs = (const int*)d_in[1];
    const int*   csr  = (const int*)d_in[2];
    float*       out  = (float*)d_out;
    int N = in_sizes[0];
    int E = in_sizes[1];
    int S = out_size;

    int F  = E / MSC;                                   // full superchunks
    int E0 = F * MSC;
    int nwin = (N + (1 << WSHIFT) - 1) >> WSHIFT;       // 16 for N = 2^22

    if (F > 0)
        prodseg_main<<<NBLK, BLK, 0, stream>>>(x, ptrs, csr, out, E, S, F, nwin);
    if (E0 < E) {
        int nt = (E - E0 + TK - 1) / TK;
        prodseg_tail<<<(nt + 255) / 256, 256, 0, stream>>>(x, ptrs, csr, out, E0, E, S);
    }
}

// Round 4
// 296.507 us; speedup vs baseline: 1.7374x; 1.1247x over previous
//
#include <hip/hip_runtime.h>

// Sorted-segment product: out[i] = prod_{j: csr[j]==i} x[ptrs[j]], empty -> 0.
//
// R4: R3's window-phased gather (FETCH 1.39GB -> 421MB) kept; fix the spill
// (R3: VGPR=64 == pt[32]+g[32] alone -> scratch traffic, WRITE 51->133MB)
// and the 44% occupancy by halving per-thread state and doubling the block:
//   EPT 32->16, BLK 512->1024. Same 16384-edge superchunk, same 64KB LDS
//   mirror, same 512 persistent blocks (2/CU), same 1MB windows, 2 gens.
// 32 waves/CU (100% occ) now hide the phased-gather latency.

#define EPT       16              // edges per thread (pt[16]+g[16] = 32 VGPRs)
#define EPT_SHIFT 4
#define BLK       1024            // threads per block (16 waves)
#define MSC       (BLK * EPT)     // 16384 edges per superchunk
#define NBLK      512             // persistent blocks (2 per CU)
#define WSHIFT    18              // window = 2^18 floats = 1 MB

__global__ __launch_bounds__(BLK, 4) void prodseg_main(
    const float* __restrict__ x,
    const int*   __restrict__ ptrs,
    const int*   __restrict__ csr,
    float*       __restrict__ out,
    int E, int S, int F /* # full superchunks */, int nwin)
{
    __shared__ float gbuf[MSC];   // column-major: edge (t,k) -> gbuf[k*BLK + t]
    const int t = threadIdx.x;
    const int ngen = (F + (int)gridDim.x - 1) / (int)gridDim.x;

    for (int gen = 0; gen < ngen; ++gen) {
        int sc = gen * (int)gridDim.x + (int)blockIdx.x;
        if (sc >= F) break;                    // block-uniform exit
        const int sbase = sc * MSC;
        const int gbase = sbase + t * EPT;

        // ---- stage my 16 ptrs into registers (vectorized, aligned) ----
        int pt[EPT];
        {
            const int4* p4 = reinterpret_cast<const int4*>(ptrs + gbase);
            #pragma unroll
            for (int i = 0; i < EPT / 4; ++i) {
                int4 v = p4[i];
                pt[4*i+0] = v.x; pt[4*i+1] = v.y;
                pt[4*i+2] = v.z; pt[4*i+3] = v.w;
            }
        }

        // ---- window-phased gather ----
        float g[EPT];
        for (int w = 0; w < nwin; ++w) {
            // 1) predicated loads only — independent, all issue (MLP)
            #pragma unroll
            for (int k = 0; k < EPT; ++k)
                if ((pt[k] >> WSHIFT) == w) g[k] = x[pt[k]];
            // 2) mirror to LDS for cross-thread run walks
            #pragma unroll
            for (int k = 0; k < EPT; ++k)
                if ((pt[k] >> WSHIFT) == w) gbuf[k * BLK + t] = g[k];
            // keep the block's waves phase-aligned (L2 locality); the final
            // one also orders gbuf writes before product-phase reads
            __syncthreads();
        }

        // ---- product phase (run ownership, exact) ----
        int prev = (gbase == 0) ? -1 : csr[gbase - 1];
        const int4* c4 = reinterpret_cast<const int4*>(csr + gbase);
        int cur = 0; bool own = false; float prod = 1.0f;
        #pragma unroll
        for (int i = 0; i < EPT / 4; ++i) {
            int4 c = c4[i];
            int sv[4] = {c.x, c.y, c.z, c.w};
            #pragma unroll
            for (int j = 0; j < 4; ++j) {
                const int k = 4 * i + j;
                int sg = sv[j];
                if (k == 0) {
                    cur = sg; own = (sg != prev);
                    prod = own ? g[0] : 1.0f;
                    if (own)
                        for (int q = prev + 1; q < cur; ++q) out[q] = 0.0f;
                } else {
                    if (sg == cur) {
                        prod *= g[k];          // harmless if !own (never stored)
                    } else {
                        if (own) out[cur] = prod;
                        for (int q = cur + 1; q < sg; ++q) out[q] = 0.0f;
                        cur = sg; own = true; prod = g[k];
                    }
                }
            }
        }
        // final run: walk forward; in-superchunk values come from LDS
        if (own) {
            int idx = gbase + EPT;
            while (idx < E) {
                if (csr[idx] != cur) break;
                float v;
                int local = idx - sbase;
                if (local < MSC)
                    v = gbuf[(local & (EPT - 1)) * BLK + (local >> EPT_SHIFT)];
                else
                    v = x[ptrs[idx]];
                prod *= v; ++idx;
            }
            out[cur] = prod;
            if (idx == E)
                for (int q = cur + 1; q < S; ++q) out[q] = 0.0f;
        }
        __syncthreads();   // protect gbuf before next generation
    }
}

// Generic tail (E % MSC != 0) — R1-proven logic; not launched for E = 2^24.
#define TK 8
__global__ __launch_bounds__(256) void prodseg_tail(
    const float* __restrict__ x,
    const int*   __restrict__ ptrs,
    const int*   __restrict__ csr,
    float*       __restrict__ out,
    int E0, int E, int S)
{
    int t = blockIdx.x * blockDim.x + threadIdx.x;
    int base = E0 + t * TK;
    if (base >= E) return;
    int prev = (base == 0) ? -1 : csr[base - 1];
    int n = (base + TK <= E) ? TK : (E - base);

    int cur = 0; bool own = false; float prod = 1.0f;
    for (int k = 0; k < n; ++k) {
        int sg = csr[base + k];
        float gv = x[ptrs[base + k]];
        if (k == 0) {
            cur = sg; own = (sg != prev);
            prod = own ? gv : 1.0f;
            if (own) for (int q = prev + 1; q < cur; ++q) out[q] = 0.0f;
        } else if (sg == cur) {
            prod *= gv;
        } else {
            if (own) out[cur] = prod;
            for (int q = cur + 1; q < sg; ++q) out[q] = 0.0f;
            cur = sg; own = true; prod = gv;
        }
    }
    if (own) {
        int idx = base + n;
        while (idx < E && csr[idx] == cur) { prod *= x[ptrs[idx]]; ++idx; }
        out[cur] = prod;
        if (idx == E) for (int q = cur + 1; q < S; ++q) out[q] = 0.0f;
    }
}

extern "C" void kernel_launch(void* const* d_in, const int* in_sizes, int n_in,
                              void* d_out, int out_size, void* d_ws, size_t ws_size,
                              hipStream_t stream) {
    const float* x    = (const float*)d_in[0];
    const int*   ptrs = (const int*)d_in[1];
    const int*   csr  = (const int*)d_in[2];
    float*       out  = (float*)d_out;
    int N = in_sizes[0];
    int E = in_sizes[1];
    int S = out_size;

    int F  = E / MSC;                                   // full superchunks
    int E0 = F * MSC;
    int nwin = (N + (1 << WSHIFT) - 1) >> WSHIFT;       // 16 for N = 2^22

    if (F > 0)
        prodseg_main<<<NBLK, BLK, 0, stream>>>(x, ptrs, csr, out, E, S, F, nwin);
    if (E0 < E) {
        int nt = (E - E0 + TK - 1) / TK;
        prodseg_tail<<<(nt + 255) / 256, 256, 0, stream>>>(x, ptrs, csr, out, E0, E, S);
    }
}